// Round 9
// baseline (200.215 us; speedup 1.0000x reference)
//
#include <hip/hip_runtime.h>
#include <hip/hip_bf16.h>

#define TB 256
#define LOG2E  1.44269504088896f
#define LOG2E2 2.88539008177793f

typedef __attribute__((ext_vector_type(8))) short bf16x8;
typedef __attribute__((ext_vector_type(4))) float f32x4;

// f32 pair -> packed bf16x2 (RNE) via v_cvt_pk_bf16_f32 (intrinsic, not asm)
__device__ __forceinline__ unsigned pk2(float a, float b){
  float2 t; t.x = a; t.y = b;
  __hip_bfloat162 h = __float22bfloat162_rn(t);
  union { __hip_bfloat162 h; unsigned u; } cv; cv.h = h; return cv.u;
}
__device__ __forceinline__ bf16x8 cvt8(float4 a, float4 b){
  union { unsigned u[4]; bf16x8 v; } r;
  r.u[0] = pk2(a.x, a.y); r.u[1] = pk2(a.z, a.w);
  r.u[2] = pk2(b.x, b.y); r.u[3] = pk2(b.z, b.w);
  return r.v;
}
// sigm(z) with pre-scaled arg: s = rcp(1 + exp2(arg)), arg = -log2e*z
__device__ __forceinline__ float sig2(float arg){
  return __builtin_amdgcn_rcpf(1.f + __builtin_amdgcn_exp2f(arg));
}
// tanh(z) with arg = 2*log2e*z:  1 - 2/(1+exp2(arg))
__device__ __forceinline__ float tanh2(float arg){
  return 1.f - 2.f*__builtin_amdgcn_rcpf(1.f + __builtin_amdgcn_exp2f(arg));
}

// async global->LDS, 16B per lane; LDS dest is wave-uniform base (+lane*16 by HW)
#define GLD16(gp, lp) __builtin_amdgcn_global_load_lds( \
    (const __attribute__((address_space(1))) void*)(gp), \
    (__attribute__((address_space(3))) void*)(lp), 16, 0, 0)

// ---------------------------------------------------------------------------
// k_prep: bf16-convert + permute weights into MFMA B-fragment order.
// Fragment chunk for (tile t, kf, lane l): W[t*16+(l&15)][kf*32+(l>>4)*8 + 0..7]
// WxG/WhG GROUP-major: group tt (0..7) = tiles {tt, 8+tt, 16+tt} contiguous.
// ---------------------------------------------------------------------------
__global__ __launch_bounds__(TB)
void k_prep(const float* __restrict__ Wioux, const float* __restrict__ Wiouh,
            const float* __restrict__ Wfx,   const float* __restrict__ Wfh,
            const float* __restrict__ bioux, const float* __restrict__ biouh,
            short* __restrict__ WxG, short* __restrict__ WhG,
            short* __restrict__ WfxP, short* __restrict__ WfhP,
            float* __restrict__ biasS){
  const int q = blockIdx.x*TB + threadIdx.x;
  const int t = q >> 8, rem = q & 255;
  const int kf = rem >> 6, lane = rem & 63;
  const int row = t*16 + (lane & 15);
  const int col = kf*32 + (lane >> 4)*8;
  const size_t src = (size_t)row*128 + col;
  if (q < 6144){                       // 24 tiles of Wioux/Wiouh
    const int g = t & 7, kind = t >> 3;
    const size_t dst = ((size_t)(g*3 + kind)*4 + kf)*512 + (size_t)lane*8;
    const float4* p  = (const float4*)(Wioux + src);
    *(bf16x8*)(WxG + dst) = cvt8(p[0], p[1]);
    const float4* p2 = (const float4*)(Wiouh + src);
    *(bf16x8*)(WhG + dst) = cvt8(p2[0], p2[1]);
  }
  if (q < 2048){                       // 8 tiles of Wfx/Wfh
    const size_t dst = ((size_t)t*4 + kf)*512 + (size_t)lane*8;
    const float4* p  = (const float4*)(Wfx + src);
    *(bf16x8*)(WfxP + dst) = cvt8(p[0], p[1]);
    const float4* p2 = (const float4*)(Wfh + src);
    *(bf16x8*)(WfhP + dst) = cvt8(p2[0], p2[1]);
  }
  if (q < 384){
    const float s = (q < 256) ? -LOG2E : LOG2E2;
    biasS[q] = s*(bioux[q] + biouh[q]);
  }
}

// FXS[p][c] = -log2e * (x_p @ W_fx^T + bfx + bfh)[c]  for all internal nodes
__global__ __launch_bounds__(TB, 4)
void k_fx(const float* __restrict__ x, const short* __restrict__ WfxP,
          const float* __restrict__ bfx, const float* __restrict__ bfh,
          float* __restrict__ FXS, int nrows){
  const int tid = threadIdx.x, wave = tid >> 6, lane = tid & 63;
  const int l15 = lane & 15, lhi = lane >> 4;
  const int mrow = (blockIdx.x*4 + wave)*16;
  const int arow = min(mrow + l15, nrows - 1);
  bf16x8 ax[4];
  const float* rp = x + (size_t)arow*128;
  #pragma unroll
  for (int kf = 0; kf < 4; ++kf){
    const float4* p = (const float4*)(rp + kf*32 + lhi*8);
    ax[kf] = cvt8(p[0], p[1]);
  }
  #pragma unroll
  for (int t = 0; t < 8; ++t){
    f32x4 acc = {0.f,0.f,0.f,0.f};
    #pragma unroll
    for (int kf = 0; kf < 4; ++kf){
      bf16x8 b = *(const bf16x8*)(WfxP + ((size_t)(t*4 + kf)*64 + lane)*8);
      acc = __builtin_amdgcn_mfma_f32_16x16x32_bf16(ax[kf], b, acc, 0,0,0);
    }
    const int col = t*16 + l15;
    const float bc = bfx[col] + bfh[col];
    #pragma unroll
    for (int r = 0; r < 4; ++r){
      const int row = mrow + lhi*4 + r;
      if (row < nrows) FXS[(size_t)row*128 + col] = -LOG2E*(acc[r] + bc);
    }
  }
}

// ---------------------------------------------------------------------------
// k_leaf: level-6. 4 waves x 16 rows. IOU weights staged group-wise, dbuf.
// R4-proven register structure: cv f32 in regs, h -> separate hbuf during
// gates (packed-reg variants R5/R7/R8 all went to scratch). LDS 40 KB =
// exactly 4 blocks/CU; launch_bounds(256,4) caps 128 VGPR (observed ~60-80).
// ---------------------------------------------------------------------------
__global__ __launch_bounds__(TB, 4)
void k_leaf(const float* __restrict__ x, int xoff,
            const short* __restrict__ WxG, const short* __restrict__ WfhP,
            const float* __restrict__ biasS, const float* __restrict__ FXS,
            int poff, short* __restrict__ HSout, float* __restrict__ FCout)
{
  __shared__ __align__(16) short wbuf[2][6144];   // 24 KB IOU group dbuf
  __shared__ __align__(16) short hbuf[4][2048];   // 16 KB per-wave swizzled h
  const int tid = threadIdx.x;
  const int wave = tid >> 6, lane = tid & 63;
  const int l15 = lane & 15, lhi = lane >> 4;
  const int mrow = (blockIdx.x*4 + wave)*16;      // exact: 262144 % 64 == 0

  bf16x8 ax[4];
  {
    const float* rp = x + (size_t)(xoff + mrow + l15)*128;
    #pragma unroll
    for (int kf = 0; kf < 4; ++kf){
      const float4* p = (const float4*)(rp + kf*32 + lhi*8);
      ax[kf] = cvt8(p[0], p[1]);
    }
  }

  #define STAGE_L(g, b) { \
    _Pragma("unroll") \
    for (int c = 0; c < 3; ++c){ \
      const int ch = c*4 + wave; \
      GLD16(WxG + (size_t)(g)*6144 + ch*512 + lane*8, &wbuf[b][ch*512]); \
    } }

  STAGE_L(0, 0);

  float cv[8][4];
  const int p = (mrow >> 3) + (lhi >> 1);
  const float* fxp = FXS + (size_t)(poff + p)*128 + l15;
  char* hbw = (char*)hbuf[wave];

  #pragma unroll
  for (int tt = 0; tt < 8; ++tt){
    __syncthreads();                  // drains stage(tt) [vmcnt(0) before barrier]
    if (tt < 7) STAGE_L(tt+1, (tt+1)&1);
    const short* wb = wbuf[tt & 1];

    f32x4 ai = {0.f,0.f,0.f,0.f}, ao = ai, au = ai;
    #pragma unroll
    for (int kf = 0; kf < 4; ++kf){
      bf16x8 bi = *(const bf16x8*)(wb + 0*2048 + kf*512 + lane*8);
      bf16x8 bo = *(const bf16x8*)(wb + 1*2048 + kf*512 + lane*8);
      bf16x8 bu = *(const bf16x8*)(wb + 2*2048 + kf*512 + lane*8);
      ai = __builtin_amdgcn_mfma_f32_16x16x32_bf16(ax[kf], bi, ai, 0,0,0);
      ao = __builtin_amdgcn_mfma_f32_16x16x32_bf16(ax[kf], bo, ao, 0,0,0);
      au = __builtin_amdgcn_mfma_f32_16x16x32_bf16(ax[kf], bu, au, 0,0,0);
    }

    const int col = tt*16 + l15;
    const float bis = biasS[col], bos = biasS[128 + col], bus = biasS[256 + col];
    float hv[4];
    float hs = 0.f;
    #pragma unroll
    for (int r = 0; r < 4; ++r){
      const float iv = sig2 (__builtin_fmaf(ai[r], -LOG2E, bis));
      const float uv = tanh2(__builtin_fmaf(au[r],  LOG2E2, bus));
      const float ov = sig2 (__builtin_fmaf(ao[r], -LOG2E, bos));
      const float c  = iv*uv;                    // leaf: fc_sum = 0
      const float h  = ov*tanh2(LOG2E2*c);
      cv[tt][r] = c;
      hv[r] = h;
      hs += h;
    }
    // packed bf16 conversion (1 cvt_pk per pair), swizzled per-row stores
    const unsigned hp01 = pk2(hv[0], hv[1]);
    const unsigned hp23 = pk2(hv[2], hv[3]);
    const int cx = col*2;
    const int r0 = lhi*4;
    *(short*)(hbw + (r0  )*256 + (cx ^ ((r0  ) << 4))) = (short)hp01;
    *(short*)(hbw + (r0+1)*256 + (cx ^ ((r0+1) << 4))) = (short)(hp01 >> 16);
    *(short*)(hbw + (r0+2)*256 + (cx ^ ((r0+2) << 4))) = (short)hp23;
    *(short*)(hbw + (r0+3)*256 + (cx ^ ((r0+3) << 4))) = (short)(hp23 >> 16);

    hs += __shfl_xor(hs, 16);
    if ((lhi & 1) == 0) HSout[(size_t)p*128 + col] = (short)pk2(hs, hs);
  }

  // ---- FH = h @ W_fh^T (B direct from global; 32 KB, L1-hot) ----
  bf16x8 af[4];
  #pragma unroll
  for (int kf = 0; kf < 4; ++kf){
    const int byte = l15*256 + (((kf*32 + lhi*8)*2) ^ (l15 << 4));
    af[kf] = *(const bf16x8*)((const char*)hbw + byte);
  }
  #pragma unroll
  for (int t2 = 0; t2 < 8; ++t2){
    f32x4 fa = {0.f,0.f,0.f,0.f};
    #pragma unroll
    for (int kf = 0; kf < 4; ++kf){
      bf16x8 b = *(const bf16x8*)(WfhP + ((size_t)(t2*4 + kf)*64 + lane)*8);
      fa = __builtin_amdgcn_mfma_f32_16x16x32_bf16(af[kf], b, fa, 0,0,0);
    }
    const float fxv = fxp[t2*16];     // = -log2e*(FX + bfx + bfh)
    float fs = 0.f;
    #pragma unroll
    for (int r = 0; r < 4; ++r){
      const float f = sig2(__builtin_fmaf(fa[r], -LOG2E, fxv));
      fs += f * cv[t2][r];
    }
    fs += __shfl_xor(fs, 16);
    if ((lhi & 1) == 0) FCout[(size_t)p*128 + t2*16 + l15] = fs;
  }
  #undef STAGE_L
}

// ---------------------------------------------------------------------------
// k_node: internal levels l=5..3. 16 rows/wave, 6-tile groups dbuf (48 KB);
// h-tile aliased onto wbuf after main loop. cv kept f32 (|c| grows w/ level).
// ---------------------------------------------------------------------------
__global__ __launch_bounds__(TB, 3)
void k_node(const float* __restrict__ x, int xoff,
            const short* __restrict__ HSin, const float* __restrict__ FCin,
            const short* __restrict__ WxG, const short* __restrict__ WhG,
            const short* __restrict__ WfhP,
            const float* __restrict__ biasS, const float* __restrict__ FXS,
            int poff, short* __restrict__ HSout, float* __restrict__ FCout,
            int nnodes)
{
  __shared__ __align__(16) short wbuf[2][12288];  // 48 KB (Wx|Wh group x2)
  const int tid = threadIdx.x;
  const int wave = tid >> 6, lane = tid & 63;
  const int l15 = lane & 15, lhi = lane >> 4;
  const int mrow = (blockIdx.x*4 + wave)*16;      // n_l divisible by 64 for l>=3
  const int arow = min(mrow + l15, nnodes - 1);

  bf16x8 ax[4], ah[4];
  {
    const float* rp = x + (size_t)(xoff + arow)*128;
    #pragma unroll
    for (int kf = 0; kf < 4; ++kf){
      const float4* p = (const float4*)(rp + kf*32 + lhi*8);
      ax[kf] = cvt8(p[0], p[1]);
    }
    const short* hp = HSin + (size_t)arow*128;
    #pragma unroll
    for (int kf = 0; kf < 4; ++kf)
      ah[kf] = *(const bf16x8*)(hp + kf*32 + lhi*8);
  }

  #define STAGE_N(g, b) { \
    _Pragma("unroll") \
    for (int c = 0; c < 3; ++c){ \
      const int ch = c*4 + wave; \
      GLD16(WxG + (size_t)(g)*6144 + ch*512 + lane*8, &wbuf[b][ch*512]); \
      GLD16(WhG + (size_t)(g)*6144 + ch*512 + lane*8, &wbuf[b][6144 + ch*512]); \
    } }

  STAGE_N(0, 0);

  float cv[8][4];
  unsigned hpk[8][2];
  const int p = (mrow >> 3) + (lhi >> 1);
  const float* fxp = FXS + (size_t)(poff + p)*128 + l15;

  #pragma unroll
  for (int tt = 0; tt < 8; ++tt){
    __syncthreads();
    if (tt < 7) STAGE_N(tt+1, (tt+1)&1);
    const short* wb = wbuf[tt & 1];

    f32x4 ai = {0.f,0.f,0.f,0.f}, ao = ai, au = ai;
    #pragma unroll
    for (int kf = 0; kf < 4; ++kf){
      bf16x8 bi = *(const bf16x8*)(wb + 0*2048 + kf*512 + lane*8);
      bf16x8 bo = *(const bf16x8*)(wb + 1*2048 + kf*512 + lane*8);
      bf16x8 bu = *(const bf16x8*)(wb + 2*2048 + kf*512 + lane*8);
      ai = __builtin_amdgcn_mfma_f32_16x16x32_bf16(ax[kf], bi, ai, 0,0,0);
      ao = __builtin_amdgcn_mfma_f32_16x16x32_bf16(ax[kf], bo, ao, 0,0,0);
      au = __builtin_amdgcn_mfma_f32_16x16x32_bf16(ax[kf], bu, au, 0,0,0);
    }
    #pragma unroll
    for (int kf = 0; kf < 4; ++kf){
      bf16x8 bi = *(const bf16x8*)(wb + 6144 + 0*2048 + kf*512 + lane*8);
      bf16x8 bo = *(const bf16x8*)(wb + 6144 + 1*2048 + kf*512 + lane*8);
      bf16x8 bu = *(const bf16x8*)(wb + 6144 + 2*2048 + kf*512 + lane*8);
      ai = __builtin_amdgcn_mfma_f32_16x16x32_bf16(ah[kf], bi, ai, 0,0,0);
      ao = __builtin_amdgcn_mfma_f32_16x16x32_bf16(ah[kf], bo, ao, 0,0,0);
      au = __builtin_amdgcn_mfma_f32_16x16x32_bf16(ah[kf], bu, au, 0,0,0);
    }

    const int col = tt*16 + l15;
    const float bis = biasS[col], bos = biasS[128 + col], bus = biasS[256 + col];
    float hv[4];
    float hs = 0.f;
    #pragma unroll
    for (int r = 0; r < 4; ++r){
      const float fc = FCin[(size_t)(mrow + lhi*4 + r)*128 + col];
      const float iv = sig2 (__builtin_fmaf(ai[r], -LOG2E, bis));
      const float uv = tanh2(__builtin_fmaf(au[r],  LOG2E2, bus));
      const float ov = sig2 (__builtin_fmaf(ao[r], -LOG2E, bos));
      const float c  = __builtin_fmaf(iv, uv, fc);
      const float h  = ov*tanh2(LOG2E2*c);
      cv[tt][r] = c;
      hv[r] = h;
      hs += h;
    }
    hpk[tt][0] = pk2(hv[0], hv[1]);
    hpk[tt][1] = pk2(hv[2], hv[3]);
    hs += __shfl_xor(hs, 16);
    if ((lhi & 1) == 0) HSout[(size_t)p*128 + col] = (short)pk2(hs, hs);
  }

  __syncthreads();
  char* hbw = (char*)(((short*)wbuf) + wave*2048);
  #pragma unroll
  for (int t2 = 0; t2 < 8; ++t2){
    const int cx = (t2*16 + l15)*2;
    const int r0 = lhi*4;
    *(short*)(hbw + (r0  )*256 + (cx ^ ((r0  ) << 4))) = (short)hpk[t2][0];
    *(short*)(hbw + (r0+1)*256 + (cx ^ ((r0+1) << 4))) = (short)(hpk[t2][0] >> 16);
    *(short*)(hbw + (r0+2)*256 + (cx ^ ((r0+2) << 4))) = (short)hpk[t2][1];
    *(short*)(hbw + (r0+3)*256 + (cx ^ ((r0+3) << 4))) = (short)(hpk[t2][1] >> 16);
  }
  bf16x8 af[4];
  #pragma unroll
  for (int kf = 0; kf < 4; ++kf){
    const int byte = l15*256 + (((kf*32 + lhi*8)*2) ^ (l15 << 4));
    af[kf] = *(const bf16x8*)((const char*)hbw + byte);
  }
  #pragma unroll
  for (int t2 = 0; t2 < 8; ++t2){
    f32x4 fa = {0.f,0.f,0.f,0.f};
    #pragma unroll
    for (int kf = 0; kf < 4; ++kf){
      bf16x8 b = *(const bf16x8*)(WfhP + ((size_t)(t2*4 + kf)*64 + lane)*8);
      fa = __builtin_amdgcn_mfma_f32_16x16x32_bf16(af[kf], b, fa, 0,0,0);
    }
    const float fxv = fxp[t2*16];
    float fs = 0.f;
    #pragma unroll
    for (int r = 0; r < 4; ++r){
      const float f = sig2(__builtin_fmaf(fa[r], -LOG2E, fxv));
      fs += f * cv[t2][r];
    }
    fs += __shfl_xor(fs, 16);
    if ((lhi & 1) == 0) FCout[(size_t)p*128 + t2*16 + l15] = fs;
  }
  #undef STAGE_N
}

// ---------------------------------------------------------------------------
// k_tail: levels 2..0 (73 nodes) in ONE block. B-frags direct from global
// (weights L1/L2-hot); level hand-off through global ws + __syncthreads.
// ---------------------------------------------------------------------------
__device__ __forceinline__ void tail_level(
    const float* __restrict__ x, int xoff,
    const short* __restrict__ HSin, const float* __restrict__ FCin,
    const short* __restrict__ WxG, const short* __restrict__ WhG,
    const short* __restrict__ WfhP,
    const float* __restrict__ biasS, const float* __restrict__ FXS, int poff,
    short* __restrict__ HSout, float* __restrict__ FCout,
    float* __restrict__ dout, int nnodes, short* __restrict__ hb)
{
  const int tid = threadIdx.x;
  const int lane = tid & 63;
  const int l15 = lane & 15, lhi = lane >> 4;
  const int mrow = (tid >> 6)*16;
  const int arow = min(mrow + l15, nnodes - 1);

  bf16x8 ax[4], ah[4];
  {
    const float* rp = x + (size_t)(xoff + arow)*128;
    #pragma unroll
    for (int kf = 0; kf < 4; ++kf){
      const float4* p = (const float4*)(rp + kf*32 + lhi*8);
      ax[kf] = cvt8(p[0], p[1]);
    }
    const short* hp = HSin + (size_t)arow*128;
    #pragma unroll
    for (int kf = 0; kf < 4; ++kf)
      ah[kf] = *(const bf16x8*)(hp + kf*32 + lhi*8);
  }

  float cv[8][4];
  const int p = (min(mrow, nnodes - 1) >> 3) + (lhi >> 1);
  const float* fxp = FXS + (size_t)(poff + min(p, (nnodes - 1) >> 3))*128 + l15;

  #pragma unroll
  for (int tt = 0; tt < 8; ++tt){
    f32x4 ai = {0.f,0.f,0.f,0.f}, ao = ai, au = ai;
    #pragma unroll
    for (int kf = 0; kf < 4; ++kf){
      bf16x8 bxi = *(const bf16x8*)(WxG + ((size_t)(tt*3 + 0)*4 + kf)*512 + lane*8);
      bf16x8 bxo = *(const bf16x8*)(WxG + ((size_t)(tt*3 + 1)*4 + kf)*512 + lane*8);
      bf16x8 bxu = *(const bf16x8*)(WxG + ((size_t)(tt*3 + 2)*4 + kf)*512 + lane*8);
      ai = __builtin_amdgcn_mfma_f32_16x16x32_bf16(ax[kf], bxi, ai, 0,0,0);
      ao = __builtin_amdgcn_mfma_f32_16x16x32_bf16(ax[kf], bxo, ao, 0,0,0);
      au = __builtin_amdgcn_mfma_f32_16x16x32_bf16(ax[kf], bxu, au, 0,0,0);
      bf16x8 bhi = *(const bf16x8*)(WhG + ((size_t)(tt*3 + 0)*4 + kf)*512 + lane*8);
      bf16x8 bho = *(const bf16x8*)(WhG + ((size_t)(tt*3 + 1)*4 + kf)*512 + lane*8);
      bf16x8 bhu = *(const bf16x8*)(WhG + ((size_t)(tt*3 + 2)*4 + kf)*512 + lane*8);
      ai = __builtin_amdgcn_mfma_f32_16x16x32_bf16(ah[kf], bhi, ai, 0,0,0);
      ao = __builtin_amdgcn_mfma_f32_16x16x32_bf16(ah[kf], bho, ao, 0,0,0);
      au = __builtin_amdgcn_mfma_f32_16x16x32_bf16(ah[kf], bhu, au, 0,0,0);
    }
    const int col = tt*16 + l15;
    const float bis = biasS[col], bos = biasS[128 + col], bus = biasS[256 + col];
    float hs = 0.f;
    #pragma unroll
    for (int r = 0; r < 4; ++r){
      const int row = lhi*4 + r;
      const int loc = min(mrow + row, nnodes - 1);
      const float fc = FCin[(size_t)loc*128 + col];
      const float iv = sig2 (__builtin_fmaf(ai[r], -LOG2E, bis));
      const float uv = tanh2(__builtin_fmaf(au[r],  LOG2E2, bus));
      const float ov = sig2 (__builtin_fmaf(ao[r], -LOG2E, bos));
      const float c  = __builtin_fmaf(iv, uv, fc);
      const float h  = ov*tanh2(LOG2E2*c);
      cv[tt][r] = c;
      hs += h;
      const int byte = row*256 + ((l15*2 + tt*32) ^ (row << 4));
      *(short*)((char*)hb + byte) = (short)pk2(h, h);
      if (dout && (mrow + row) == 0){ dout[col] = c; dout[128 + col] = h; }
    }
    if (HSout){
      hs += __shfl_xor(hs, 16);
      if ((lhi & 1) == 0){
        const int pv = (lhi == 0) ? (mrow < nnodes) : (mrow + 8 < nnodes);
        if (pv) HSout[(size_t)p*128 + col] = (short)pk2(hs, hs);
      }
    }
  }
  if (!HSout) return;   // root: uniform exit

  bf16x8 af[4];
  #pragma unroll
  for (int kf = 0; kf < 4; ++kf){
    const int byte = l15*256 + (((kf*32 + lhi*8)*2) ^ (l15 << 4));
    af[kf] = *(const bf16x8*)((const char*)hb + byte);
  }
  #pragma unroll
  for (int t2 = 0; t2 < 8; ++t2){
    f32x4 fa = {0.f,0.f,0.f,0.f};
    #pragma unroll
    for (int kf = 0; kf < 4; ++kf){
      bf16x8 b = *(const bf16x8*)(WfhP + ((size_t)(t2*4 + kf)*64 + lane)*8);
      fa = __builtin_amdgcn_mfma_f32_16x16x32_bf16(af[kf], b, fa, 0,0,0);
    }
    const float fxv = fxp[t2*16];
    float fs = 0.f;
    #pragma unroll
    for (int r = 0; r < 4; ++r){
      const float f = sig2(__builtin_fmaf(fa[r], -LOG2E, fxv));
      fs += f * cv[t2][r];
    }
    fs += __shfl_xor(fs, 16);
    if ((lhi & 1) == 0){
      const int pv = (lhi == 0) ? (mrow < nnodes) : (mrow + 8 < nnodes);
      if (pv) FCout[(size_t)p*128 + t2*16 + l15] = fs;
    }
  }
}

__global__ __launch_bounds__(TB, 1)
void k_tail(const float* __restrict__ x,
            const short* __restrict__ WxG, const short* __restrict__ WhG,
            const short* __restrict__ WfhP,
            const float* __restrict__ biasS, const float* __restrict__ FXS,
            short* __restrict__ HS0, short* __restrict__ HS1,
            float* __restrict__ FC0, float* __restrict__ FC1,
            float* __restrict__ dout)
{
  __shared__ __align__(16) short hbuf[4][2048];
  short* hb = hbuf[threadIdx.x >> 6];
  // l=2: 64 nodes @ xoff 9, poff 1; reads HS0/FC0 (from l=3), writes HS1/FC1
  tail_level(x, 9, HS0, FC0, WxG, WhG, WfhP, biasS, FXS, 1, HS1, FC1, nullptr, 64, hb);
  __syncthreads();
  // l=1: 8 nodes @ xoff 1, poff 0; reads HS1/FC1, writes HS0/FC0
  tail_level(x, 1, HS1, FC1, WxG, WhG, WfhP, biasS, FXS, 0, HS0, FC0, nullptr, 8, hb);
  __syncthreads();
  // l=0: root @ xoff 0; reads HS0/FC0 -> dout
  tail_level(x, 0, HS0, FC0, WxG, WhG, WfhP, biasS, FXS, 0, nullptr, nullptr, dout, 1, hb);
}

extern "C" void kernel_launch(void* const* d_in, const int* in_sizes, int n_in,
                              void* d_out, int out_size, void* d_ws, size_t ws_size,
                              hipStream_t stream)
{
  const float* x     = (const float*)d_in[0];
  const float* Wioux = (const float*)d_in[1];
  const float* bioux = (const float*)d_in[2];
  const float* Wiouh = (const float*)d_in[3];
  const float* biouh = (const float*)d_in[4];
  const float* Wfx   = (const float*)d_in[5];
  const float* bfx   = (const float*)d_in[6];
  const float* Wfh   = (const float*)d_in[7];
  const float* bfh   = (const float*)d_in[8];
  float* dout = (float*)d_out;

  static const int n_l[7]   = {1, 8, 64, 512, 4096, 32768, 262144};
  static const int off_l[7] = {0, 1, 9, 73, 585, 4681, 37449};

  char* base = (char*)d_ws;
  size_t off = 0;
  auto take = [&](size_t bytes)->char*{
    char* r = base + off;
    off = (off + bytes + 255) & ~(size_t)255;
    return r;
  };
  float* FXS  = (float*)take((size_t)37449*128*4);
  float* FC0  = (float*)take((size_t)32768*128*4);
  float* FC1  = (float*)take((size_t)32768*128*4);
  short* HS0  = (short*)take((size_t)32768*128*2);
  short* HS1  = (short*)take((size_t)32768*128*2);
  short* WxG  = (short*)take((size_t)24*2048*2);
  short* WhG  = (short*)take((size_t)24*2048*2);
  short* WfxP = (short*)take((size_t)8*2048*2);
  short* WfhP = (short*)take((size_t)8*2048*2);
  float* biasS= (float*)take((size_t)384*4);
  if (off > ws_size) return;

  short* HS[2] = {HS0, HS1};
  float* FC[2] = {FC0, FC1};

  k_prep<<<24, TB, 0, stream>>>(Wioux, Wiouh, Wfx, Wfh, bioux, biouh,
                                WxG, WhG, WfxP, WfhP, biasS);
  k_fx<<<(37449 + 63)/64, TB, 0, stream>>>(x, WfxP, bfx, bfh, FXS, 37449);

  // leaf (l=6): writes HS1/FC1 (l=5 reads HS[5&1]=HS1)
  k_leaf<<<262144/64, TB, 0, stream>>>(x, off_l[6], WxG, WfhP, biasS, FXS,
                                       off_l[5], HS1, FC1);

  for (int l = 5; l >= 3; --l){
    const int n = n_l[l];
    k_node<<<(n + 63)/64, TB, 0, stream>>>(
      x, off_l[l], HS[l & 1], FC[l & 1],
      WxG, WhG, WfhP, biasS, FXS,
      off_l[l-1], HS[(l & 1) ^ 1], FC[(l & 1) ^ 1], n);
  }
  // levels 2..0 fused (l=3 wrote HS[(3&1)^1] = HS0)
  k_tail<<<1, TB, 0, stream>>>(x, WxG, WhG, WfhP, biasS, FXS,
                               HS0, HS1, FC0, FC1, dout);
}

// Round 10
// 193.700 us; speedup vs baseline: 1.0336x; 1.0336x over previous
//
#include <hip/hip_runtime.h>
#include <hip/hip_bf16.h>

#define TB 256
#define LOG2E  1.44269504088896f
#define LOG2E2 2.88539008177793f

typedef __attribute__((ext_vector_type(8))) short bf16x8;
typedef __attribute__((ext_vector_type(4))) float f32x4;

// f32 pair -> packed bf16x2 (RNE) via v_cvt_pk_bf16_f32 (intrinsic, not asm)
__device__ __forceinline__ unsigned pk2(float a, float b){
  float2 t; t.x = a; t.y = b;
  __hip_bfloat162 h = __float22bfloat162_rn(t);
  union { __hip_bfloat162 h; unsigned u; } cv; cv.h = h; return cv.u;
}
__device__ __forceinline__ bf16x8 cvt8(float4 a, float4 b){
  union { unsigned u[4]; bf16x8 v; } r;
  r.u[0] = pk2(a.x, a.y); r.u[1] = pk2(a.z, a.w);
  r.u[2] = pk2(b.x, b.y); r.u[3] = pk2(b.z, b.w);
  return r.v;
}
// sigm(z) with pre-scaled arg: s = rcp(1 + exp2(arg)), arg = -log2e*z
__device__ __forceinline__ float sig2(float arg){
  return __builtin_amdgcn_rcpf(1.f + __builtin_amdgcn_exp2f(arg));
}
// tanh(z) with arg = 2*log2e*z:  1 - 2/(1+exp2(arg))
__device__ __forceinline__ float tanh2(float arg){
  return 1.f - 2.f*__builtin_amdgcn_rcpf(1.f + __builtin_amdgcn_exp2f(arg));
}

// async global->LDS, 16B per lane; LDS dest is wave-uniform base (+lane*16 by HW)
#define GLD16(gp, lp) __builtin_amdgcn_global_load_lds( \
    (const __attribute__((address_space(1))) void*)(gp), \
    (__attribute__((address_space(3))) void*)(lp), 16, 0, 0)

// ---------------------------------------------------------------------------
// k_prep: bf16-convert + permute weights into MFMA B-fragment order.
// Fragment chunk for (tile t, kf, lane l): W[t*16+(l&15)][kf*32+(l>>4)*8 + 0..7]
// WxG/WhG GROUP-major: group tt (0..7) = tiles {tt, 8+tt, 16+tt} contiguous.
// ---------------------------------------------------------------------------
__global__ __launch_bounds__(TB)
void k_prep(const float* __restrict__ Wioux, const float* __restrict__ Wiouh,
            const float* __restrict__ Wfx,   const float* __restrict__ Wfh,
            const float* __restrict__ bioux, const float* __restrict__ biouh,
            short* __restrict__ WxG, short* __restrict__ WhG,
            short* __restrict__ WfxP, short* __restrict__ WfhP,
            float* __restrict__ biasS){
  const int q = blockIdx.x*TB + threadIdx.x;
  const int t = q >> 8, rem = q & 255;
  const int kf = rem >> 6, lane = rem & 63;
  const int row = t*16 + (lane & 15);
  const int col = kf*32 + (lane >> 4)*8;
  const size_t src = (size_t)row*128 + col;
  if (q < 6144){                       // 24 tiles of Wioux/Wiouh
    const int g = t & 7, kind = t >> 3;
    const size_t dst = ((size_t)(g*3 + kind)*4 + kf)*512 + (size_t)lane*8;
    const float4* p  = (const float4*)(Wioux + src);
    *(bf16x8*)(WxG + dst) = cvt8(p[0], p[1]);
    const float4* p2 = (const float4*)(Wiouh + src);
    *(bf16x8*)(WhG + dst) = cvt8(p2[0], p2[1]);
  }
  if (q < 2048){                       // 8 tiles of Wfx/Wfh
    const size_t dst = ((size_t)t*4 + kf)*512 + (size_t)lane*8;
    const float4* p  = (const float4*)(Wfx + src);
    *(bf16x8*)(WfxP + dst) = cvt8(p[0], p[1]);
    const float4* p2 = (const float4*)(Wfh + src);
    *(bf16x8*)(WfhP + dst) = cvt8(p2[0], p2[1]);
  }
  if (q < 384){
    const float s = (q < 256) ? -LOG2E : LOG2E2;
    biasS[q] = s*(bioux[q] + biouh[q]);
  }
}

// FXS[p][c] = -log2e * (x_p @ W_fx^T + bfx + bfh)[c]  for all internal nodes
__global__ __launch_bounds__(TB, 4)
void k_fx(const float* __restrict__ x, const short* __restrict__ WfxP,
          const float* __restrict__ bfx, const float* __restrict__ bfh,
          float* __restrict__ FXS, int nrows){
  const int tid = threadIdx.x, wave = tid >> 6, lane = tid & 63;
  const int l15 = lane & 15, lhi = lane >> 4;
  const int mrow = (blockIdx.x*4 + wave)*16;
  const int arow = min(mrow + l15, nrows - 1);
  bf16x8 ax[4];
  const float* rp = x + (size_t)arow*128;
  #pragma unroll
  for (int kf = 0; kf < 4; ++kf){
    const float4* p = (const float4*)(rp + kf*32 + lhi*8);
    ax[kf] = cvt8(p[0], p[1]);
  }
  #pragma unroll
  for (int t = 0; t < 8; ++t){
    f32x4 acc = {0.f,0.f,0.f,0.f};
    #pragma unroll
    for (int kf = 0; kf < 4; ++kf){
      bf16x8 b = *(const bf16x8*)(WfxP + ((size_t)(t*4 + kf)*64 + lane)*8);
      acc = __builtin_amdgcn_mfma_f32_16x16x32_bf16(ax[kf], b, acc, 0,0,0);
    }
    const int col = t*16 + l15;
    const float bc = bfx[col] + bfh[col];
    #pragma unroll
    for (int r = 0; r < 4; ++r){
      const int row = mrow + lhi*4 + r;
      if (row < nrows) FXS[(size_t)row*128 + col] = -LOG2E*(acc[r] + bc);
    }
  }
}

// ---------------------------------------------------------------------------
// k_leaf: level-6. 4 waves x 16 rows. SINGLE-buffered 12 KB wbuf with T14
// reg-staging (issue global loads early; ds_write after compute barrier).
// LDS = 12 + 16 (hbuf) = 28 KB -> 5 blocks/CU (R9's 40 KB capped us at 4;
// occupancy was the residual limiter: VALU 42%, MFMA 13%, LDS 23%).
// cv stays plain f32 in regs (packed-array variants R5/R7/R8 all spilled).
// ---------------------------------------------------------------------------
__global__ __launch_bounds__(TB, 4)
void k_leaf(const float* __restrict__ x, int xoff,
            const short* __restrict__ WxG, const short* __restrict__ WfhP,
            const float* __restrict__ biasS, const float* __restrict__ FXS,
            int poff, short* __restrict__ HSout, float* __restrict__ FCout)
{
  __shared__ __align__(16) short wbuf[6144];      // 12 KB: one IOU group
  __shared__ __align__(16) short hbuf[4][2048];   // 16 KB per-wave swizzled h
  const int tid = threadIdx.x;
  const int wave = tid >> 6, lane = tid & 63;
  const int l15 = lane & 15, lhi = lane >> 4;
  const int mrow = (blockIdx.x*4 + wave)*16;      // exact: 262144 % 64 == 0

  bf16x8 ax[4];
  {
    const float* rp = x + (size_t)(xoff + mrow + l15)*128;
    #pragma unroll
    for (int kf = 0; kf < 4; ++kf){
      const float4* p = (const float4*)(rp + kf*32 + lhi*8);
      ax[kf] = cvt8(p[0], p[1]);
    }
  }

  // reg-staging: each thread owns 3x16B of the 12 KB group
  bf16x8 rg0, rg1, rg2;
  #define LOADG(g) { \
    const short* s_ = WxG + (size_t)(g)*6144 + tid*8; \
    rg0 = *(const bf16x8*)(s_); \
    rg1 = *(const bf16x8*)(s_ + 2048); \
    rg2 = *(const bf16x8*)(s_ + 4096); }
  #define WRITEG() { \
    *(bf16x8*)(wbuf + tid*8)        = rg0; \
    *(bf16x8*)(wbuf + 2048 + tid*8) = rg1; \
    *(bf16x8*)(wbuf + 4096 + tid*8) = rg2; }

  LOADG(0);
  WRITEG();
  __syncthreads();                    // group 0 visible

  float cv[8][4];
  const int p = (mrow >> 3) + (lhi >> 1);
  const float* fxp = FXS + (size_t)(poff + p)*128 + l15;
  char* hbw = (char*)hbuf[wave];

  #pragma unroll
  for (int tt = 0; tt < 8; ++tt){
    if (tt < 7) LOADG(tt+1);          // T14: issue early, hide under compute

    f32x4 ai = {0.f,0.f,0.f,0.f}, ao = ai, au = ai;
    #pragma unroll
    for (int kf = 0; kf < 4; ++kf){
      bf16x8 bi = *(const bf16x8*)(wbuf + 0*2048 + kf*512 + lane*8);
      bf16x8 bo = *(const bf16x8*)(wbuf + 1*2048 + kf*512 + lane*8);
      bf16x8 bu = *(const bf16x8*)(wbuf + 2*2048 + kf*512 + lane*8);
      ai = __builtin_amdgcn_mfma_f32_16x16x32_bf16(ax[kf], bi, ai, 0,0,0);
      ao = __builtin_amdgcn_mfma_f32_16x16x32_bf16(ax[kf], bo, ao, 0,0,0);
      au = __builtin_amdgcn_mfma_f32_16x16x32_bf16(ax[kf], bu, au, 0,0,0);
    }

    const int col = tt*16 + l15;
    const float bis = biasS[col], bos = biasS[128 + col], bus = biasS[256 + col];
    float hv[4];
    float hs = 0.f;
    #pragma unroll
    for (int r = 0; r < 4; ++r){
      const float iv = sig2 (__builtin_fmaf(ai[r], -LOG2E, bis));
      const float uv = tanh2(__builtin_fmaf(au[r],  LOG2E2, bus));
      const float ov = sig2 (__builtin_fmaf(ao[r], -LOG2E, bos));
      const float c  = iv*uv;                    // leaf: fc_sum = 0
      const float h  = ov*tanh2(LOG2E2*c);
      cv[tt][r] = c;
      hv[r] = h;
      hs += h;
    }
    const unsigned hp01 = pk2(hv[0], hv[1]);
    const unsigned hp23 = pk2(hv[2], hv[3]);
    const int cx = col*2;
    const int r0 = lhi*4;
    *(short*)(hbw + (r0  )*256 + (cx ^ ((r0  ) << 4))) = (short)hp01;
    *(short*)(hbw + (r0+1)*256 + (cx ^ ((r0+1) << 4))) = (short)(hp01 >> 16);
    *(short*)(hbw + (r0+2)*256 + (cx ^ ((r0+2) << 4))) = (short)hp23;
    *(short*)(hbw + (r0+3)*256 + (cx ^ ((r0+3) << 4))) = (short)(hp23 >> 16);

    hs += __shfl_xor(hs, 16);
    if ((lhi & 1) == 0) HSout[(size_t)p*128 + col] = (short)pk2(hs, hs);

    __syncthreads();                  // all waves done reading wbuf(tt)
    if (tt < 7){
      WRITEG();                       // publish group tt+1
      __syncthreads();
    }
  }

  // ---- FH = h @ W_fh^T (B direct from global; 32 KB, L1-hot) ----
  bf16x8 af[4];
  #pragma unroll
  for (int kf = 0; kf < 4; ++kf){
    const int byte = l15*256 + (((kf*32 + lhi*8)*2) ^ (l15 << 4));
    af[kf] = *(const bf16x8*)((const char*)hbw + byte);
  }
  #pragma unroll
  for (int t2 = 0; t2 < 8; ++t2){
    f32x4 fa = {0.f,0.f,0.f,0.f};
    #pragma unroll
    for (int kf = 0; kf < 4; ++kf){
      bf16x8 b = *(const bf16x8*)(WfhP + ((size_t)(t2*4 + kf)*64 + lane)*8);
      fa = __builtin_amdgcn_mfma_f32_16x16x32_bf16(af[kf], b, fa, 0,0,0);
    }
    const float fxv = fxp[t2*16];     // = -log2e*(FX + bfx + bfh)
    float fs = 0.f;
    #pragma unroll
    for (int r = 0; r < 4; ++r){
      const float f = sig2(__builtin_fmaf(fa[r], -LOG2E, fxv));
      fs += f * cv[t2][r];
    }
    fs += __shfl_xor(fs, 16);
    if ((lhi & 1) == 0) FCout[(size_t)p*128 + t2*16 + l15] = fs;
  }
  #undef LOADG
  #undef WRITEG
}

// ---------------------------------------------------------------------------
// k_node: internal levels l=5..3. 16 rows/wave, 6-tile groups dbuf (48 KB);
// h-tile aliased onto wbuf after main loop. cv kept f32 (|c| grows w/ level).
// ---------------------------------------------------------------------------
__global__ __launch_bounds__(TB, 3)
void k_node(const float* __restrict__ x, int xoff,
            const short* __restrict__ HSin, const float* __restrict__ FCin,
            const short* __restrict__ WxG, const short* __restrict__ WhG,
            const short* __restrict__ WfhP,
            const float* __restrict__ biasS, const float* __restrict__ FXS,
            int poff, short* __restrict__ HSout, float* __restrict__ FCout,
            int nnodes)
{
  __shared__ __align__(16) short wbuf[2][12288];  // 48 KB (Wx|Wh group x2)
  const int tid = threadIdx.x;
  const int wave = tid >> 6, lane = tid & 63;
  const int l15 = lane & 15, lhi = lane >> 4;
  const int mrow = (blockIdx.x*4 + wave)*16;      // n_l divisible by 64 for l>=3
  const int arow = min(mrow + l15, nnodes - 1);

  bf16x8 ax[4], ah[4];
  {
    const float* rp = x + (size_t)(xoff + arow)*128;
    #pragma unroll
    for (int kf = 0; kf < 4; ++kf){
      const float4* p = (const float4*)(rp + kf*32 + lhi*8);
      ax[kf] = cvt8(p[0], p[1]);
    }
    const short* hp = HSin + (size_t)arow*128;
    #pragma unroll
    for (int kf = 0; kf < 4; ++kf)
      ah[kf] = *(const bf16x8*)(hp + kf*32 + lhi*8);
  }

  #define STAGE_N(g, b) { \
    _Pragma("unroll") \
    for (int c = 0; c < 3; ++c){ \
      const int ch = c*4 + wave; \
      GLD16(WxG + (size_t)(g)*6144 + ch*512 + lane*8, &wbuf[b][ch*512]); \
      GLD16(WhG + (size_t)(g)*6144 + ch*512 + lane*8, &wbuf[b][6144 + ch*512]); \
    } }

  STAGE_N(0, 0);

  float cv[8][4];
  unsigned hpk[8][2];
  const int p = (mrow >> 3) + (lhi >> 1);
  const float* fxp = FXS + (size_t)(poff + p)*128 + l15;

  #pragma unroll
  for (int tt = 0; tt < 8; ++tt){
    __syncthreads();
    if (tt < 7) STAGE_N(tt+1, (tt+1)&1);
    const short* wb = wbuf[tt & 1];

    f32x4 ai = {0.f,0.f,0.f,0.f}, ao = ai, au = ai;
    #pragma unroll
    for (int kf = 0; kf < 4; ++kf){
      bf16x8 bi = *(const bf16x8*)(wb + 0*2048 + kf*512 + lane*8);
      bf16x8 bo = *(const bf16x8*)(wb + 1*2048 + kf*512 + lane*8);
      bf16x8 bu = *(const bf16x8*)(wb + 2*2048 + kf*512 + lane*8);
      ai = __builtin_amdgcn_mfma_f32_16x16x32_bf16(ax[kf], bi, ai, 0,0,0);
      ao = __builtin_amdgcn_mfma_f32_16x16x32_bf16(ax[kf], bo, ao, 0,0,0);
      au = __builtin_amdgcn_mfma_f32_16x16x32_bf16(ax[kf], bu, au, 0,0,0);
    }
    #pragma unroll
    for (int kf = 0; kf < 4; ++kf){
      bf16x8 bi = *(const bf16x8*)(wb + 6144 + 0*2048 + kf*512 + lane*8);
      bf16x8 bo = *(const bf16x8*)(wb + 6144 + 1*2048 + kf*512 + lane*8);
      bf16x8 bu = *(const bf16x8*)(wb + 6144 + 2*2048 + kf*512 + lane*8);
      ai = __builtin_amdgcn_mfma_f32_16x16x32_bf16(ah[kf], bi, ai, 0,0,0);
      ao = __builtin_amdgcn_mfma_f32_16x16x32_bf16(ah[kf], bo, ao, 0,0,0);
      au = __builtin_amdgcn_mfma_f32_16x16x32_bf16(ah[kf], bu, au, 0,0,0);
    }

    const int col = tt*16 + l15;
    const float bis = biasS[col], bos = biasS[128 + col], bus = biasS[256 + col];
    float hv[4];
    float hs = 0.f;
    #pragma unroll
    for (int r = 0; r < 4; ++r){
      const float fc = FCin[(size_t)(mrow + lhi*4 + r)*128 + col];
      const float iv = sig2 (__builtin_fmaf(ai[r], -LOG2E, bis));
      const float uv = tanh2(__builtin_fmaf(au[r],  LOG2E2, bus));
      const float ov = sig2 (__builtin_fmaf(ao[r], -LOG2E, bos));
      const float c  = __builtin_fmaf(iv, uv, fc);
      const float h  = ov*tanh2(LOG2E2*c);
      cv[tt][r] = c;
      hv[r] = h;
      hs += h;
    }
    hpk[tt][0] = pk2(hv[0], hv[1]);
    hpk[tt][1] = pk2(hv[2], hv[3]);
    hs += __shfl_xor(hs, 16);
    if ((lhi & 1) == 0) HSout[(size_t)p*128 + col] = (short)pk2(hs, hs);
  }

  __syncthreads();
  char* hbw = (char*)(((short*)wbuf) + wave*2048);
  #pragma unroll
  for (int t2 = 0; t2 < 8; ++t2){
    const int cx = (t2*16 + l15)*2;
    const int r0 = lhi*4;
    *(short*)(hbw + (r0  )*256 + (cx ^ ((r0  ) << 4))) = (short)hpk[t2][0];
    *(short*)(hbw + (r0+1)*256 + (cx ^ ((r0+1) << 4))) = (short)(hpk[t2][0] >> 16);
    *(short*)(hbw + (r0+2)*256 + (cx ^ ((r0+2) << 4))) = (short)hpk[t2][1];
    *(short*)(hbw + (r0+3)*256 + (cx ^ ((r0+3) << 4))) = (short)(hpk[t2][1] >> 16);
  }
  bf16x8 af[4];
  #pragma unroll
  for (int kf = 0; kf < 4; ++kf){
    const int byte = l15*256 + (((kf*32 + lhi*8)*2) ^ (l15 << 4));
    af[kf] = *(const bf16x8*)((const char*)hbw + byte);
  }
  #pragma unroll
  for (int t2 = 0; t2 < 8; ++t2){
    f32x4 fa = {0.f,0.f,0.f,0.f};
    #pragma unroll
    for (int kf = 0; kf < 4; ++kf){
      bf16x8 b = *(const bf16x8*)(WfhP + ((size_t)(t2*4 + kf)*64 + lane)*8);
      fa = __builtin_amdgcn_mfma_f32_16x16x32_bf16(af[kf], b, fa, 0,0,0);
    }
    const float fxv = fxp[t2*16];
    float fs = 0.f;
    #pragma unroll
    for (int r = 0; r < 4; ++r){
      const float f = sig2(__builtin_fmaf(fa[r], -LOG2E, fxv));
      fs += f * cv[t2][r];
    }
    fs += __shfl_xor(fs, 16);
    if ((lhi & 1) == 0) FCout[(size_t)p*128 + t2*16 + l15] = fs;
  }
  #undef STAGE_N
}

// ---------------------------------------------------------------------------
// k_tail: levels 2..0 (73 nodes) in ONE block. B-frags direct from global
// (weights L1/L2-hot); level hand-off through global ws + __syncthreads.
// ---------------------------------------------------------------------------
__device__ __forceinline__ void tail_level(
    const float* __restrict__ x, int xoff,
    const short* __restrict__ HSin, const float* __restrict__ FCin,
    const short* __restrict__ WxG, const short* __restrict__ WhG,
    const short* __restrict__ WfhP,
    const float* __restrict__ biasS, const float* __restrict__ FXS, int poff,
    short* __restrict__ HSout, float* __restrict__ FCout,
    float* __restrict__ dout, int nnodes, short* __restrict__ hb)
{
  const int tid = threadIdx.x;
  const int lane = tid & 63;
  const int l15 = lane & 15, lhi = lane >> 4;
  const int mrow = (tid >> 6)*16;
  const int arow = min(mrow + l15, nnodes - 1);

  bf16x8 ax[4], ah[4];
  {
    const float* rp = x + (size_t)(xoff + arow)*128;
    #pragma unroll
    for (int kf = 0; kf < 4; ++kf){
      const float4* p = (const float4*)(rp + kf*32 + lhi*8);
      ax[kf] = cvt8(p[0], p[1]);
    }
    const short* hp = HSin + (size_t)arow*128;
    #pragma unroll
    for (int kf = 0; kf < 4; ++kf)
      ah[kf] = *(const bf16x8*)(hp + kf*32 + lhi*8);
  }

  float cv[8][4];
  const int p = (min(mrow, nnodes - 1) >> 3) + (lhi >> 1);
  const float* fxp = FXS + (size_t)(poff + min(p, (nnodes - 1) >> 3))*128 + l15;

  #pragma unroll
  for (int tt = 0; tt < 8; ++tt){
    f32x4 ai = {0.f,0.f,0.f,0.f}, ao = ai, au = ai;
    #pragma unroll
    for (int kf = 0; kf < 4; ++kf){
      bf16x8 bxi = *(const bf16x8*)(WxG + ((size_t)(tt*3 + 0)*4 + kf)*512 + lane*8);
      bf16x8 bxo = *(const bf16x8*)(WxG + ((size_t)(tt*3 + 1)*4 + kf)*512 + lane*8);
      bf16x8 bxu = *(const bf16x8*)(WxG + ((size_t)(tt*3 + 2)*4 + kf)*512 + lane*8);
      ai = __builtin_amdgcn_mfma_f32_16x16x32_bf16(ax[kf], bxi, ai, 0,0,0);
      ao = __builtin_amdgcn_mfma_f32_16x16x32_bf16(ax[kf], bxo, ao, 0,0,0);
      au = __builtin_amdgcn_mfma_f32_16x16x32_bf16(ax[kf], bxu, au, 0,0,0);
      bf16x8 bhi = *(const bf16x8*)(WhG + ((size_t)(tt*3 + 0)*4 + kf)*512 + lane*8);
      bf16x8 bho = *(const bf16x8*)(WhG + ((size_t)(tt*3 + 1)*4 + kf)*512 + lane*8);
      bf16x8 bhu = *(const bf16x8*)(WhG + ((size_t)(tt*3 + 2)*4 + kf)*512 + lane*8);
      ai = __builtin_amdgcn_mfma_f32_16x16x32_bf16(ah[kf], bhi, ai, 0,0,0);
      ao = __builtin_amdgcn_mfma_f32_16x16x32_bf16(ah[kf], bho, ao, 0,0,0);
      au = __builtin_amdgcn_mfma_f32_16x16x32_bf16(ah[kf], bhu, au, 0,0,0);
    }
    const int col = tt*16 + l15;
    const float bis = biasS[col], bos = biasS[128 + col], bus = biasS[256 + col];
    float hs = 0.f;
    #pragma unroll
    for (int r = 0; r < 4; ++r){
      const int row = lhi*4 + r;
      const int loc = min(mrow + row, nnodes - 1);
      const float fc = FCin[(size_t)loc*128 + col];
      const float iv = sig2 (__builtin_fmaf(ai[r], -LOG2E, bis));
      const float uv = tanh2(__builtin_fmaf(au[r],  LOG2E2, bus));
      const float ov = sig2 (__builtin_fmaf(ao[r], -LOG2E, bos));
      const float c  = __builtin_fmaf(iv, uv, fc);
      const float h  = ov*tanh2(LOG2E2*c);
      cv[tt][r] = c;
      hs += h;
      const int byte = row*256 + ((l15*2 + tt*32) ^ (row << 4));
      *(short*)((char*)hb + byte) = (short)pk2(h, h);
      if (dout && (mrow + row) == 0){ dout[col] = c; dout[128 + col] = h; }
    }
    if (HSout){
      hs += __shfl_xor(hs, 16);
      if ((lhi & 1) == 0){
        const int pv = (lhi == 0) ? (mrow < nnodes) : (mrow + 8 < nnodes);
        if (pv) HSout[(size_t)p*128 + col] = (short)pk2(hs, hs);
      }
    }
  }
  if (!HSout) return;   // root: uniform exit

  bf16x8 af[4];
  #pragma unroll
  for (int kf = 0; kf < 4; ++kf){
    const int byte = l15*256 + (((kf*32 + lhi*8)*2) ^ (l15 << 4));
    af[kf] = *(const bf16x8*)((const char*)hb + byte);
  }
  #pragma unroll
  for (int t2 = 0; t2 < 8; ++t2){
    f32x4 fa = {0.f,0.f,0.f,0.f};
    #pragma unroll
    for (int kf = 0; kf < 4; ++kf){
      bf16x8 b = *(const bf16x8*)(WfhP + ((size_t)(t2*4 + kf)*64 + lane)*8);
      fa = __builtin_amdgcn_mfma_f32_16x16x32_bf16(af[kf], b, fa, 0,0,0);
    }
    const float fxv = fxp[t2*16];
    float fs = 0.f;
    #pragma unroll
    for (int r = 0; r < 4; ++r){
      const float f = sig2(__builtin_fmaf(fa[r], -LOG2E, fxv));
      fs += f * cv[t2][r];
    }
    fs += __shfl_xor(fs, 16);
    if ((lhi & 1) == 0){
      const int pv = (lhi == 0) ? (mrow < nnodes) : (mrow + 8 < nnodes);
      if (pv) FCout[(size_t)p*128 + t2*16 + l15] = fs;
    }
  }
}

__global__ __launch_bounds__(TB, 1)
void k_tail(const float* __restrict__ x,
            const short* __restrict__ WxG, const short* __restrict__ WhG,
            const short* __restrict__ WfhP,
            const float* __restrict__ biasS, const float* __restrict__ FXS,
            short* __restrict__ HS0, short* __restrict__ HS1,
            float* __restrict__ FC0, float* __restrict__ FC1,
            float* __restrict__ dout)
{
  __shared__ __align__(16) short hbuf[4][2048];
  short* hb = hbuf[threadIdx.x >> 6];
  // l=2: 64 nodes @ xoff 9, poff 1; reads HS0/FC0 (from l=3), writes HS1/FC1
  tail_level(x, 9, HS0, FC0, WxG, WhG, WfhP, biasS, FXS, 1, HS1, FC1, nullptr, 64, hb);
  __syncthreads();
  // l=1: 8 nodes @ xoff 1, poff 0; reads HS1/FC1, writes HS0/FC0
  tail_level(x, 1, HS1, FC1, WxG, WhG, WfhP, biasS, FXS, 0, HS0, FC0, nullptr, 8, hb);
  __syncthreads();
  // l=0: root @ xoff 0; reads HS0/FC0 -> dout
  tail_level(x, 0, HS0, FC0, WxG, WhG, WfhP, biasS, FXS, 0, nullptr, nullptr, dout, 1, hb);
}

extern "C" void kernel_launch(void* const* d_in, const int* in_sizes, int n_in,
                              void* d_out, int out_size, void* d_ws, size_t ws_size,
                              hipStream_t stream)
{
  const float* x     = (const float*)d_in[0];
  const float* Wioux = (const float*)d_in[1];
  const float* bioux = (const float*)d_in[2];
  const float* Wiouh = (const float*)d_in[3];
  const float* biouh = (const float*)d_in[4];
  const float* Wfx   = (const float*)d_in[5];
  const float* bfx   = (const float*)d_in[6];
  const float* Wfh   = (const float*)d_in[7];
  const float* bfh   = (const float*)d_in[8];
  float* dout = (float*)d_out;

  static const int n_l[7]   = {1, 8, 64, 512, 4096, 32768, 262144};
  static const int off_l[7] = {0, 1, 9, 73, 585, 4681, 37449};

  char* base = (char*)d_ws;
  size_t off = 0;
  auto take = [&](size_t bytes)->char*{
    char* r = base + off;
    off = (off + bytes + 255) & ~(size_t)255;
    return r;
  };
  float* FXS  = (float*)take((size_t)37449*128*4);
  float* FC0  = (float*)take((size_t)32768*128*4);
  float* FC1  = (float*)take((size_t)32768*128*4);
  short* HS0  = (short*)take((size_t)32768*128*2);
  short* HS1  = (short*)take((size_t)32768*128*2);
  short* WxG  = (short*)take((size_t)24*2048*2);
  short* WhG  = (short*)take((size_t)24*2048*2);
  short* WfxP = (short*)take((size_t)8*2048*2);
  short* WfhP = (short*)take((size_t)8*2048*2);
  float* biasS= (float*)take((size_t)384*4);
  if (off > ws_size) return;

  short* HS[2] = {HS0, HS1};
  float* FC[2] = {FC0, FC1};

  k_prep<<<24, TB, 0, stream>>>(Wioux, Wiouh, Wfx, Wfh, bioux, biouh,
                                WxG, WhG, WfxP, WfhP, biasS);
  k_fx<<<(37449 + 63)/64, TB, 0, stream>>>(x, WfxP, bfx, bfh, FXS, 37449);

  // leaf (l=6): writes HS1/FC1 (l=5 reads HS[5&1]=HS1)
  k_leaf<<<262144/64, TB, 0, stream>>>(x, off_l[6], WxG, WfhP, biasS, FXS,
                                       off_l[5], HS1, FC1);

  for (int l = 5; l >= 3; --l){
    const int n = n_l[l];
    k_node<<<(n + 63)/64, TB, 0, stream>>>(
      x, off_l[l], HS[l & 1], FC[l & 1],
      WxG, WhG, WfhP, biasS, FXS,
      off_l[l-1], HS[(l & 1) ^ 1], FC[(l & 1) ^ 1], n);
  }
  // levels 2..0 fused (l=3 wrote HS[(3&1)^1] = HS0)
  k_tail<<<1, TB, 0, stream>>>(x, WxG, WhG, WfhP, biasS, FXS,
                               HS0, HS1, FC0, FC1, dout);
}